// Round 3
// baseline (1073.129 us; speedup 1.0000x reference)
//
#include <hip/hip_runtime.h>
#include <stdint.h>

#define NN 50000
#define EE 800000

typedef unsigned int u32;
typedef unsigned short u16;

__device__ __forceinline__ float bflo(u32 u) { return __uint_as_float(u << 16); }
__device__ __forceinline__ float bfhi(u32 u) { return __uint_as_float(u & 0xFFFF0000u); }
__device__ __forceinline__ float bf1(u16 v) { return __uint_as_float(((u32)v) << 16); }
__device__ __forceinline__ u32 f2bf(float f) {
    u32 u = __float_as_uint(f);
    return (u + 0x7FFFu + ((u >> 16) & 1u)) >> 16;
}
__device__ __forceinline__ u32 pack2(float lo, float hi) {
    return f2bf(lo) | (f2bf(hi) << 16);
}

// ---------- dtype detection: flag=1 if x is f32, 0 if bf16 ----------
// bf16-pair interpretation of f32 data: low halves are mantissa garbage ->
// ~24% have exponent >= 0xC3 (|v| >= 2^68). True bf16 N(0,1): none.

__global__ void detect_kernel(const u32* __restrict__ xw, int* __restrict__ flag) {
    int tid = threadIdx.x;
    int cnt = 0;
    for (int i = tid; i < 8192; i += 256) {
        u32 u = xw[i];
        int e0 = (u >> 7) & 0xFF, e1 = (u >> 23) & 0xFF;
        cnt += (e0 >= 0xC3) + (e1 >= 0xC3);
    }
    #pragma unroll
    for (int off = 32; off; off >>= 1) cnt += __shfl_xor(cnt, off, 64);
    __shared__ int wsum[4];
    if ((tid & 63) == 0) wsum[tid >> 6] = cnt;
    __syncthreads();
    if (tid == 0) flag[0] = (wsum[0] + wsum[1] + wsum[2] + wsum[3] > 100) ? 1 : 0;
}

// ---------- setup ----------

__global__ void count_deg_kernel(const int* __restrict__ ei, int* __restrict__ deg) {
    int e = blockIdx.x * 256 + threadIdx.x;
    if (e < EE) atomicAdd(&deg[ei[EE + e]], 1);
}

__global__ void dinv_kernel(const int* __restrict__ deg, float* __restrict__ dinv) {
    int i = blockIdx.x * 256 + threadIdx.x;
    if (i < NN) {
        int d = deg[i];
        dinv[i] = d > 0 ? rsqrtf((float)d) : 0.f;
    }
}

__global__ void scan_kernel(const int* __restrict__ deg, int* __restrict__ rowptr,
                            int* __restrict__ woff) {
    __shared__ int wsum[4];
    __shared__ int carry_s;
    int tid = threadIdx.x, lane = tid & 63, w = tid >> 6;
    if (tid == 0) carry_s = 0;
    __syncthreads();
    for (int base = 0; base < NN; base += 256) {
        int i = base + tid;
        int v = (i < NN) ? deg[i] : 0;
        int x = v;
        #pragma unroll
        for (int off = 1; off < 64; off <<= 1) {
            int y = __shfl_up(x, off, 64);
            if (lane >= off) x += y;
        }
        if (lane == 63) wsum[w] = x;
        __syncthreads();
        int add = 0;
        if (w > 0) add += wsum[0];
        if (w > 1) add += wsum[1];
        if (w > 2) add += wsum[2];
        int btot = wsum[0] + wsum[1] + wsum[2] + wsum[3];
        int excl = carry_s + add + x - v;
        if (i < NN) { rowptr[i] = excl; woff[i] = excl; }
        __syncthreads();
        if (tid == 0) carry_s += btot;
        __syncthreads();
    }
    if (tid == 0) rowptr[NN] = carry_s;
}

__global__ void bucket_kernel(const int* __restrict__ ei, int* __restrict__ woff,
                              int* __restrict__ esrc) {
    int e = blockIdx.x * 256 + threadIdx.x;
    if (e >= EE) return;
    int r = ei[e], c = ei[EE + e];
    int p = atomicAdd(&woff[c], 1);
    esrc[p] = r;
}

// ---------- imports (dtype-adaptive) ----------

__global__ void import_x_kernel(const void* __restrict__ x, u32* __restrict__ h,
                                const int* __restrict__ flag) {
    int i = blockIdx.x * 256 + threadIdx.x;
    if (i >= NN * 64) return;
    if (flag[0]) {
        const float* xf = (const float*)x;
        h[i] = pack2(xf[2 * i], xf[2 * i + 1]);
    } else {
        h[i] = ((const u32*)x)[i];
    }
}

// W [K+1][128][fout] -> wq f32 [K+1][32][fout][4]  (kq = in/4)
__global__ void wprep_kernel(const void* __restrict__ w, float* __restrict__ wq,
                             int fout, int total, const int* __restrict__ flag) {
    int idx = blockIdx.x * 256 + threadIdx.x;
    if (idx >= total) return;
    float v = flag[0] ? ((const float*)w)[idx] : bf1(((const u16*)w)[idx]);
    int per = 128 * fout;
    int k = idx / per, rem = idx % per;
    int in = rem / fout, o = rem % fout;
    wq[(size_t)k * per + (((in >> 2) * fout + o) << 2) + (in & 3)] = v;
}

__global__ void bprep_kernel(const void* __restrict__ b1, const void* __restrict__ b2,
                             float* __restrict__ bf, const int* __restrict__ flag) {
    int i = threadIdx.x;  // 192 threads
    if (i < 128) bf[i] = flag[0] ? ((const float*)b1)[i] : bf1(((const u16*)b1)[i]);
    else {
        int j = i - 128;
        bf[i] = flag[0] ? ((const float*)b2)[j] : bf1(((const u16*)b2)[j]);
    }
}

// ---------- propagation: one wave per node, bf16x2 per lane ----------

__global__ void prop_kernel(const u32* __restrict__ hin, u32* __restrict__ hout,
                            const int* __restrict__ rowptr, const int* __restrict__ esrc,
                            const float* __restrict__ dinv) {
    int node = (blockIdx.x * 256 + threadIdx.x) >> 6;
    int lane = threadIdx.x & 63;
    if (node >= NN) return;
    int e0 = rowptr[node], e1 = rowptr[node + 1];
    float dc = dinv[node];
    float ax = 0.f, ay = 0.f;
    for (int e = e0; e < e1; e++) {
        int s = esrc[e];
        float ds = dinv[s];
        u32 u = hin[(size_t)s * 64 + lane];
        ax = fmaf(ds, bflo(u), ax);
        ay = fmaf(ds, bfhi(u), ay);
    }
    hout[(size_t)node * 64 + lane] = pack2(ax * dc, ay * dc);
}

// ---------- GEMM: bf16 [N,128] @ wq f32 [32][FOUT][4] -> [N,FOUT] ----------

template <int FOUT>
__global__ __launch_bounds__(256) void gemm_kernel(const u32* __restrict__ hin,
                                                   const float* __restrict__ wq,
                                                   const float* __restrict__ bias,
                                                   void* __restrict__ outv,
                                                   int init, int accbf) {
    constexpr int RPT = FOUT / 8;
    __shared__ float hs[32 * 128];
    int tid = threadIdx.x;
    int row0 = blockIdx.x * 32;
    const uint4* src = (const uint4*)hin;
    #pragma unroll
    for (int i = 0; i < 2; i++) {
        int c = tid + 256 * i;
        int row = c >> 4, ch = c & 15;
        uint4 u = make_uint4(0, 0, 0, 0);
        if (row0 + row < NN) u = src[(size_t)row0 * 16 + c];
        float* d = hs + row * 128 + ch * 8;
        ((float4*)d)[0] = make_float4(bflo(u.x), bfhi(u.x), bflo(u.y), bfhi(u.y));
        ((float4*)d)[1] = make_float4(bflo(u.z), bfhi(u.z), bflo(u.w), bfhi(u.w));
    }
    __syncthreads();

    int tx = tid % FOUT, ty = tid / FOUT;
    float acc[RPT];
    #pragma unroll
    for (int i = 0; i < RPT; i++) acc[i] = 0.f;

    const float4* wp = (const float4*)wq;
    for (int kq = 0; kq < 32; kq++) {
        float4 wv = wp[kq * FOUT + tx];
        #pragma unroll
        for (int i = 0; i < RPT; i++) {
            const float4 hv = ((const float4*)(hs + (ty * RPT + i) * 128))[kq];
            acc[i] = fmaf(wv.x, hv.x,
                     fmaf(wv.y, hv.y,
                     fmaf(wv.z, hv.z,
                     fmaf(wv.w, hv.w, acc[i]))));
        }
    }

    float b = bias[tx];
    if (accbf) {
        u16* o = (u16*)outv;
        #pragma unroll
        for (int i = 0; i < RPT; i++) {
            int r = row0 + ty * RPT + i;
            if (r < NN) {
                size_t idx = (size_t)r * FOUT + tx;
                float v = init ? (acc[i] + b) : (bf1(o[idx]) + acc[i]);
                o[idx] = (u16)f2bf(v);
            }
        }
    } else {
        float* o = (float*)outv;
        #pragma unroll
        for (int i = 0; i < RPT; i++) {
            int r = row0 + ty * RPT + i;
            if (r < NN) {
                size_t idx = (size_t)r * FOUT + tx;
                o[idx] = init ? (acc[i] + b) : (o[idx] + acc[i]);
            }
        }
    }
}

__global__ void relu_kernel(const void* __restrict__ in, u32* __restrict__ outp, int accbf) {
    int i = blockIdx.x * 256 + threadIdx.x;
    if (i >= NN * 64) return;
    float a, b;
    if (accbf) {
        u32 u = ((const u32*)in)[i];
        a = bflo(u); b = bfhi(u);
    } else {
        float2 v = ((const float2*)in)[i];
        a = v.x; b = v.y;
    }
    outp[i] = pack2(fmaxf(a, 0.f), fmaxf(b, 0.f));
}

__global__ void logsoftmax_kernel(const void* __restrict__ in, void* __restrict__ outv,
                                  const int* __restrict__ flag, int accbf) {
    int row = (blockIdx.x * 256 + threadIdx.x) >> 6;
    int lane = threadIdx.x & 63;
    if (row >= NN) return;
    float v = accbf ? bf1(((const u16*)in)[(size_t)row * 64 + lane])
                    : ((const float*)in)[(size_t)row * 64 + lane];
    float m = v;
    #pragma unroll
    for (int off = 32; off; off >>= 1) m = fmaxf(m, __shfl_xor(m, off, 64));
    float e = __expf(v - m);
    float s = e;
    #pragma unroll
    for (int off = 32; off; off >>= 1) s += __shfl_xor(s, off, 64);
    float r = v - m - __logf(s);
    if (flag[0]) ((float*)outv)[(size_t)row * 64 + lane] = r;
    else ((u16*)outv)[(size_t)row * 64 + lane] = (u16)f2bf(r);
}

// ---------- launch ----------

extern "C" void kernel_launch(void* const* d_in, const int* in_sizes, int n_in,
                              void* d_out, int out_size, void* d_ws, size_t ws_size,
                              hipStream_t stream) {
    const void* x  = d_in[0];
    const int*  ei = (const int*)d_in[1];
    const void* W1 = d_in[2];
    const void* b1 = d_in[3];
    const void* W2 = d_in[4];
    const void* b2 = d_in[5];

    char* ws = (char*)d_ws;
    size_t p = 0;
    auto alloc = [&](size_t bytes) -> void* {
        void* r = ws + p;
        p = (p + bytes + 255) & ~(size_t)255;
        return r;
    };
    int*   flag   = (int*)  alloc(256);
    int*   deg    = (int*)  alloc((size_t)NN * 4);
    float* dinv   = (float*)alloc((size_t)NN * 4);
    int*   rowptr = (int*)  alloc((size_t)(NN + 1) * 4);
    int*   woff   = (int*)  alloc((size_t)NN * 4);
    int*   esrc   = (int*)  alloc((size_t)EE * 4);
    float* w1q    = (float*)alloc((size_t)4 * 128 * 128 * 4);
    float* w2q    = (float*)alloc((size_t)4 * 128 * 64 * 4);
    float* biasF  = (float*)alloc(192 * 4);
    u32*   hA     = (u32*)  alloc((size_t)(NN + 16) * 64 * 4);
    u32*   hB     = (u32*)  alloc((size_t)(NN + 16) * 64 * 4);
    // f32 accumulator needs 25.6 MB more; fall back to bf16 accumulator if tight
    size_t need_f32 = p + (size_t)NN * 128 * 4 + 4096;
    int accbf = (ws_size < need_f32) ? 1 : 0;
    void* outF = alloc(accbf ? (size_t)NN * 128 * 2 : (size_t)NN * 128 * 4);

    hipMemsetAsync(deg, 0, (size_t)NN * 4, stream);
    detect_kernel<<<1, 256, 0, stream>>>((const u32*)x, flag);
    count_deg_kernel<<<(EE + 255) / 256, 256, 0, stream>>>(ei, deg);
    dinv_kernel<<<(NN + 255) / 256, 256, 0, stream>>>(deg, dinv);
    scan_kernel<<<1, 256, 0, stream>>>(deg, rowptr, woff);
    bucket_kernel<<<(EE + 255) / 256, 256, 0, stream>>>(ei, woff, esrc);
    wprep_kernel<<<256, 256, 0, stream>>>(W1, w1q, 128, 4 * 128 * 128, flag);
    wprep_kernel<<<128, 256, 0, stream>>>(W2, w2q, 64, 4 * 128 * 64, flag);
    bprep_kernel<<<1, 192, 0, stream>>>(b1, b2, biasF, flag);

    const int GG = (NN + 31) / 32;
    const int PG = (NN * 64 + 255) / 256;

    import_x_kernel<<<PG, 256, 0, stream>>>(x, hA, flag);

    // layer 1: outF = sum_k (A^k x) @ W1[k] + b1
    gemm_kernel<128><<<GG, 256, 0, stream>>>(hA, w1q, biasF, outF, 1, accbf);
    prop_kernel<<<PG, 256, 0, stream>>>(hA, hB, rowptr, esrc, dinv);
    gemm_kernel<128><<<GG, 256, 0, stream>>>(hB, w1q + 1 * 16384, biasF, outF, 0, accbf);
    prop_kernel<<<PG, 256, 0, stream>>>(hB, hA, rowptr, esrc, dinv);
    gemm_kernel<128><<<GG, 256, 0, stream>>>(hA, w1q + 2 * 16384, biasF, outF, 0, accbf);
    prop_kernel<<<PG, 256, 0, stream>>>(hA, hB, rowptr, esrc, dinv);
    gemm_kernel<128><<<GG, 256, 0, stream>>>(hB, w1q + 3 * 16384, biasF, outF, 0, accbf);
    relu_kernel<<<PG, 256, 0, stream>>>(outF, hA, accbf);

    // layer 2: outF = sum_k (A^k h) @ W2[k] + b2
    gemm_kernel<64><<<GG, 256, 0, stream>>>(hA, w2q, biasF + 128, outF, 1, accbf);
    prop_kernel<<<PG, 256, 0, stream>>>(hA, hB, rowptr, esrc, dinv);
    gemm_kernel<64><<<GG, 256, 0, stream>>>(hB, w2q + 1 * 8192, biasF + 128, outF, 0, accbf);
    prop_kernel<<<PG, 256, 0, stream>>>(hB, hA, rowptr, esrc, dinv);
    gemm_kernel<64><<<GG, 256, 0, stream>>>(hA, w2q + 2 * 8192, biasF + 128, outF, 0, accbf);
    prop_kernel<<<PG, 256, 0, stream>>>(hA, hB, rowptr, esrc, dinv);
    gemm_kernel<64><<<GG, 256, 0, stream>>>(hB, w2q + 3 * 8192, biasF + 128, outF, 0, accbf);

    logsoftmax_kernel<<<PG, 256, 0, stream>>>(outF, d_out, flag, accbf);
}

// Round 4
// 463.794 us; speedup vs baseline: 2.3138x; 2.3138x over previous
//
#include <hip/hip_runtime.h>
#include <stdint.h>

#define NN 50000
#define EE 800000
#define NROWS 50048  // 782 * 64

typedef unsigned int u32;
typedef unsigned short u16;
using f32x4 = __attribute__((ext_vector_type(4))) float;
using short8 = __attribute__((ext_vector_type(8))) short;

__device__ __forceinline__ float bflo(u32 u) { return __uint_as_float(u << 16); }
__device__ __forceinline__ float bfhi(u32 u) { return __uint_as_float(u & 0xFFFF0000u); }
__device__ __forceinline__ float bf1(u16 v) { return __uint_as_float(((u32)v) << 16); }
__device__ __forceinline__ u32 f2bf(float f) {
    u32 u = __float_as_uint(f);
    return (u + 0x7FFFu + ((u >> 16) & 1u)) >> 16;
}
__device__ __forceinline__ u32 pack2(float lo, float hi) {
    return f2bf(lo) | (f2bf(hi) << 16);
}

// ---------- dtype detection: flag=1 if inputs are f32, 0 if bf16 ----------

__global__ void detect_kernel(const u32* __restrict__ xw, int* __restrict__ flag) {
    int tid = threadIdx.x;
    int cnt = 0;
    for (int i = tid; i < 8192; i += 256) {
        u32 u = xw[i];
        int e0 = (u >> 7) & 0xFF, e1 = (u >> 23) & 0xFF;
        cnt += (e0 >= 0xC3) + (e1 >= 0xC3);
    }
    #pragma unroll
    for (int off = 32; off; off >>= 1) cnt += __shfl_xor(cnt, off, 64);
    __shared__ int wsum[4];
    if ((tid & 63) == 0) wsum[tid >> 6] = cnt;
    __syncthreads();
    if (tid == 0) flag[0] = (wsum[0] + wsum[1] + wsum[2] + wsum[3] > 100) ? 1 : 0;
}

// ---------- degree / norm setup ----------

__global__ void count_deg_kernel(const int* __restrict__ ei, int* __restrict__ deg) {
    int e = blockIdx.x * 256 + threadIdx.x;
    if (e < EE) atomicAdd(&deg[ei[EE + e]], 1);
}

__global__ void dinv_kernel(const int* __restrict__ deg, float* __restrict__ dinv) {
    int i = blockIdx.x * 256 + threadIdx.x;
    if (i < NN) {
        int d = deg[i];
        dinv[i] = d > 0 ? rsqrtf((float)d) : 0.f;
    }
}

// parallel scan, 3 phases
__global__ void scan1_kernel(const int* __restrict__ deg, int* __restrict__ excl,
                             int* __restrict__ bsum) {
    int i = blockIdx.x * 256 + threadIdx.x;
    int lane = threadIdx.x & 63, w = threadIdx.x >> 6;
    int v = (i < NN) ? deg[i] : 0;
    int x = v;
    #pragma unroll
    for (int off = 1; off < 64; off <<= 1) {
        int y = __shfl_up(x, off, 64);
        if (lane >= off) x += y;
    }
    __shared__ int ws[4];
    if (lane == 63) ws[w] = x;
    __syncthreads();
    int add = 0;
    if (w > 0) add += ws[0];
    if (w > 1) add += ws[1];
    if (w > 2) add += ws[2];
    if (i < NN) excl[i] = x - v + add;
    if (threadIdx.x == 255) bsum[blockIdx.x] = x + add;
}

__global__ void scan2_kernel(int* __restrict__ bsum, int* __restrict__ boff, int nb) {
    int tid = threadIdx.x, lane = tid & 63, w = tid >> 6;
    int v = (tid < nb) ? bsum[tid] : 0;
    int x = v;
    #pragma unroll
    for (int off = 1; off < 64; off <<= 1) {
        int y = __shfl_up(x, off, 64);
        if (lane >= off) x += y;
    }
    __shared__ int ws[4];
    if (lane == 63) ws[w] = x;
    __syncthreads();
    int add = 0;
    if (w > 0) add += ws[0];
    if (w > 1) add += ws[1];
    if (w > 2) add += ws[2];
    if (tid < nb) boff[tid] = x - v + add;
}

__global__ void scan3_kernel(int* __restrict__ rowptr, const int* __restrict__ boff,
                             int* __restrict__ woff) {
    int i = blockIdx.x * 256 + threadIdx.x;
    if (i < NN) {
        int r = rowptr[i] + boff[blockIdx.x];
        rowptr[i] = r;
        woff[i] = r;
    }
    if (i == 0) rowptr[NN] = EE;
}

// erec[p] = {src, norm} bucketed by target
__global__ void bucket_kernel(const int* __restrict__ ei, const float* __restrict__ dinv,
                              int* __restrict__ woff, int2* __restrict__ erec) {
    int e = blockIdx.x * 256 + threadIdx.x;
    if (e >= EE) return;
    int r = ei[e], c = ei[EE + e];
    int p = atomicAdd(&woff[c], 1);
    erec[p] = make_int2(r, __float_as_int(dinv[r] * dinv[c]));
}

// ---------- weight prep: W [4][128][fout] -> WT bf16 [fout][512] (k = hop*128+in) ----------

__global__ void wprep_kernel(const void* __restrict__ w, u16* __restrict__ wt,
                             int fout, int total, const int* __restrict__ flag) {
    int idx = blockIdx.x * 256 + threadIdx.x;
    if (idx >= total) return;
    u16 v = flag[0] ? (u16)f2bf(((const float*)w)[idx]) : ((const u16*)w)[idx];
    int per = 128 * fout;
    int k = idx / per, rem = idx % per;
    int in = rem / fout, o = rem % fout;
    wt[(size_t)o * 512 + k * 128 + in] = v;
}

__global__ void bprep_kernel(const void* __restrict__ b1, const void* __restrict__ b2,
                             float* __restrict__ bf, const int* __restrict__ flag) {
    int i = threadIdx.x;  // 192 threads
    if (i < 128) bf[i] = flag[0] ? ((const float*)b1)[i] : bf1(((const u16*)b1)[i]);
    else {
        int j = i - 128;
        bf[i] = flag[0] ? ((const float*)b2)[j] : bf1(((const u16*)b2)[j]);
    }
}

__global__ void import_x_kernel(const void* __restrict__ x, u32* __restrict__ h,
                                const int* __restrict__ flag) {
    int i = blockIdx.x * 256 + threadIdx.x;
    if (i >= NN * 64) return;
    if (flag[0]) {
        const float* xf = (const float*)x;
        h[i] = pack2(xf[2 * i], xf[2 * i + 1]);
    } else {
        h[i] = ((const u32*)x)[i];
    }
}

// ---------- propagation: one wave per node, lane-cooperative edge records ----------

__global__ __launch_bounds__(256) void prop_kernel(const u32* __restrict__ hin,
                                                   u32* __restrict__ hout,
                                                   const int* __restrict__ rowptr,
                                                   const int2* __restrict__ erec) {
    int node = (blockIdx.x * 256 + threadIdx.x) >> 6;
    int lane = threadIdx.x & 63;
    if (node >= NN) return;
    int e0 = __builtin_amdgcn_readfirstlane(rowptr[node]);
    int e1 = __builtin_amdgcn_readfirstlane(rowptr[node + 1]);
    float ax = 0.f, ay = 0.f;
    for (int base = e0; base < e1; base += 64) {
        int2 r = make_int2(0, 0);  // src=0 (valid), norm=0.0f (no contribution)
        if (base + lane < e1) r = erec[base + lane];
        int cnt = e1 - base;
        if (cnt > 64) cnt = 64;
        cnt = (cnt + 3) & ~3;
        for (int j = 0; j < cnt; j += 4) {
            #pragma unroll
            for (int u = 0; u < 4; u++) {
                int s = __builtin_amdgcn_readlane(r.x, j + u);
                float wgt = __uint_as_float(__builtin_amdgcn_readlane(r.y, j + u));
                u32 hv = hin[(size_t)s * 64 + lane];
                ax = fmaf(wgt, bflo(hv), ax);
                ay = fmaf(wgt, bfhi(hv), ay);
            }
        }
    }
    hout[(size_t)node * 64 + lane] = pack2(ax, ay);
}

// ---------- MFMA GEMM, K=512 over 4 hop-buffers ----------

__device__ __forceinline__ short8 ld8(const void* p) {
    return __builtin_bit_cast(short8, *(const uint4*)p);
}

template <int NT>
__device__ __forceinline__ void mm_step(const u32* buf, const u16* wt, int row, int lane,
                                        int hop, f32x4* acc) {
    int qo = lane >> 4;
    #pragma unroll
    for (int q = 0; q < 4; q++) {
        short8 a = ld8(buf + (size_t)row * 64 + q * 16 + qo * 4);
        #pragma unroll
        for (int t = 0; t < NT; t++) {
            const u16* bp = wt + (size_t)(16 * t + (lane & 15)) * 512 + hop * 128 + q * 32 + qo * 8;
            short8 b = ld8(bp);
            acc[t] = __builtin_amdgcn_mfma_f32_16x16x32_bf16(a, b, acc[t], 0, 0, 0);
        }
    }
}

// layer 1: out = relu(sum_k h_k @ W1[k] + b1) -> bf16 [N,128], written into hout (may alias h0)
__global__ __launch_bounds__(256) void gemm1_kernel(const u32* h0, const u32* h1,
                                                    const u32* h2, const u32* h3,
                                                    const u16* __restrict__ wt,
                                                    const float* __restrict__ bias,
                                                    u32* hout) {
    int lane = threadIdx.x & 63, w = threadIdx.x >> 6;
    int rw = blockIdx.x * 64 + 16 * w;
    int row = rw + (lane & 15);
    f32x4 acc[8];
    #pragma unroll
    for (int t = 0; t < 8; t++) acc[t] = (f32x4){0.f, 0.f, 0.f, 0.f};
    mm_step<8>(h0, wt, row, lane, 0, acc);
    mm_step<8>(h1, wt, row, lane, 1, acc);
    mm_step<8>(h2, wt, row, lane, 2, acc);
    mm_step<8>(h3, wt, row, lane, 3, acc);
    int r0 = rw + (lane >> 4) * 4;
    int col = lane & 15;
    u16* o = (u16*)hout;
    #pragma unroll
    for (int t = 0; t < 8; t++) {
        float bs = bias[16 * t + col];
        #pragma unroll
        for (int r = 0; r < 4; r++) {
            int rr = r0 + r;
            if (rr < NN)
                o[(size_t)rr * 128 + 16 * t + col] = (u16)f2bf(fmaxf(acc[t][r] + bs, 0.f));
        }
    }
}

// layer 2: out = log_softmax(sum_k g_k @ W2[k] + b2) -> d_out (bf16 or f32 per flag)
__global__ __launch_bounds__(256) void gemm2_kernel(const u32* g0, const u32* g1,
                                                    const u32* g2, const u32* g3,
                                                    const u16* __restrict__ wt,
                                                    const float* __restrict__ bias,
                                                    void* outv, const int* __restrict__ flag) {
    int lane = threadIdx.x & 63, w = threadIdx.x >> 6;
    int rw = blockIdx.x * 64 + 16 * w;
    int row = rw + (lane & 15);
    f32x4 acc[4];
    #pragma unroll
    for (int t = 0; t < 4; t++) acc[t] = (f32x4){0.f, 0.f, 0.f, 0.f};
    mm_step<4>(g0, wt, row, lane, 0, acc);
    mm_step<4>(g1, wt, row, lane, 1, acc);
    mm_step<4>(g2, wt, row, lane, 2, acc);
    mm_step<4>(g3, wt, row, lane, 3, acc);
    int col = lane & 15;
    float bs0 = bias[col], bs1 = bias[16 + col], bs2 = bias[32 + col], bs3 = bias[48 + col];
    int r0 = rw + (lane >> 4) * 4;
    int fl = flag[0];
    #pragma unroll
    for (int r = 0; r < 4; r++) {
        float v0 = acc[0][r] + bs0, v1 = acc[1][r] + bs1;
        float v2 = acc[2][r] + bs2, v3 = acc[3][r] + bs3;
        float m = fmaxf(fmaxf(v0, v1), fmaxf(v2, v3));
        #pragma unroll
        for (int msk = 8; msk; msk >>= 1) m = fmaxf(m, __shfl_xor(m, msk, 64));
        float s = __expf(v0 - m) + __expf(v1 - m) + __expf(v2 - m) + __expf(v3 - m);
        #pragma unroll
        for (int msk = 8; msk; msk >>= 1) s += __shfl_xor(s, msk, 64);
        float lg = m + __logf(s);
        int rr = r0 + r;
        if (rr < NN) {
            size_t bidx = (size_t)rr * 64 + col;
            if (fl) {
                float* of = (float*)outv;
                of[bidx] = v0 - lg;
                of[bidx + 16] = v1 - lg;
                of[bidx + 32] = v2 - lg;
                of[bidx + 48] = v3 - lg;
            } else {
                u16* ob = (u16*)outv;
                ob[bidx] = (u16)f2bf(v0 - lg);
                ob[bidx + 16] = (u16)f2bf(v1 - lg);
                ob[bidx + 32] = (u16)f2bf(v2 - lg);
                ob[bidx + 48] = (u16)f2bf(v3 - lg);
            }
        }
    }
}

// ---------- launch ----------

extern "C" void kernel_launch(void* const* d_in, const int* in_sizes, int n_in,
                              void* d_out, int out_size, void* d_ws, size_t ws_size,
                              hipStream_t stream) {
    const void* x  = d_in[0];
    const int*  ei = (const int*)d_in[1];
    const void* W1 = d_in[2];
    const void* b1 = d_in[3];
    const void* W2 = d_in[4];
    const void* b2 = d_in[5];

    char* ws = (char*)d_ws;
    size_t p = 0;
    auto alloc = [&](size_t bytes) -> void* {
        void* r = ws + p;
        p = (p + bytes + 255) & ~(size_t)255;
        return r;
    };
    int*   flag   = (int*)  alloc(256);
    int*   deg    = (int*)  alloc((size_t)NN * 4);
    float* dinv   = (float*)alloc((size_t)NN * 4);
    int*   rowptr = (int*)  alloc((size_t)(NN + 1) * 4);
    int*   woff   = (int*)  alloc((size_t)NN * 4);
    int*   bsum   = (int*)  alloc(256 * 4);
    int*   boff   = (int*)  alloc(256 * 4);
    int2*  erec   = (int2*) alloc((size_t)EE * 8);
    u16*   wt1    = (u16*)  alloc((size_t)128 * 512 * 2);
    u16*   wt2    = (u16*)  alloc((size_t)64 * 512 * 2);
    float* biasF  = (float*)alloc(192 * 4);
    u32*   hA     = (u32*)  alloc((size_t)(NROWS + 16) * 64 * 4);
    u32*   hB     = (u32*)  alloc((size_t)(NROWS + 16) * 64 * 4);
    u32*   hC     = (u32*)  alloc((size_t)(NROWS + 16) * 64 * 4);
    u32*   hD     = (u32*)  alloc((size_t)(NROWS + 16) * 64 * 4);
    // total ~= 58.5 MB

    const int NB = (NN + 255) / 256;  // 196

    hipMemsetAsync(deg, 0, (size_t)NN * 4, stream);
    detect_kernel<<<1, 256, 0, stream>>>((const u32*)x, flag);
    count_deg_kernel<<<(EE + 255) / 256, 256, 0, stream>>>(ei, deg);
    dinv_kernel<<<NB, 256, 0, stream>>>(deg, dinv);
    scan1_kernel<<<NB, 256, 0, stream>>>(deg, rowptr, bsum);
    scan2_kernel<<<1, 256, 0, stream>>>(bsum, boff, NB);
    scan3_kernel<<<NB, 256, 0, stream>>>(rowptr, boff, woff);
    bucket_kernel<<<(EE + 255) / 256, 256, 0, stream>>>(ei, dinv, woff, erec);
    wprep_kernel<<<(4 * 128 * 128 + 255) / 256, 256, 0, stream>>>(W1, wt1, 128, 4 * 128 * 128, flag);
    wprep_kernel<<<(4 * 128 * 64 + 255) / 256, 256, 0, stream>>>(W2, wt2, 64, 4 * 128 * 64, flag);
    bprep_kernel<<<1, 192, 0, stream>>>(b1, b2, biasF, flag);

    const int PG = (NN * 64) / 256;   // 12500: one wave per node
    const int GG = NROWS / 64;        // 782

    import_x_kernel<<<PG, 256, 0, stream>>>(x, hA, flag);

    // layer 1: h_k = A^k x, k=0..3; fused GEMM + bias + relu -> hA (bf16)
    prop_kernel<<<PG, 256, 0, stream>>>(hA, hB, rowptr, erec);
    prop_kernel<<<PG, 256, 0, stream>>>(hB, hC, rowptr, erec);
    prop_kernel<<<PG, 256, 0, stream>>>(hC, hD, rowptr, erec);
    gemm1_kernel<<<GG, 256, 0, stream>>>(hA, hB, hC, hD, wt1, biasF, hA);

    // layer 2: g_k = A^k h; fused GEMM + bias + log_softmax -> d_out
    prop_kernel<<<PG, 256, 0, stream>>>(hA, hB, rowptr, erec);
    prop_kernel<<<PG, 256, 0, stream>>>(hB, hC, rowptr, erec);
    prop_kernel<<<PG, 256, 0, stream>>>(hC, hD, rowptr, erec);
    gemm2_kernel<<<GG, 256, 0, stream>>>(hA, hB, hC, hD, wt2, biasF + 128, d_out, flag);
}